// Round 10
// baseline (1441.483 us; speedup 1.0000x reference)
//
#include <hip/hip_runtime.h>
#include <hip/hip_fp16.h>

#define BATCH 32
#define SEQ   1024
#define DIM   512

typedef _Float16 f16x8 __attribute__((ext_vector_type(8)));
typedef float    f32x4 __attribute__((ext_vector_type(4)));
typedef unsigned int u32x4 __attribute__((ext_vector_type(4)));

union UU4 { uint4 s; u32x4 v; };

static __device__ __forceinline__ float tanh_fast(float x) {
    float e = __expf(2.0f * x);
    return 1.0f - 2.0f / (e + 1.0f);
}

// Consumer gate: wait until both col-halves of (batch,stripe) xw are published.
static __device__ __forceinline__ void gate_wait(unsigned int* flags, int idx) {
    if (threadIdx.x == 0) {
        while (__hip_atomic_load(&flags[idx], __ATOMIC_ACQUIRE,
                                 __HIP_MEMORY_SCOPE_AGENT) < 2u)
            __builtin_amdgcn_s_sleep(8);
    }
    __syncthreads();
}

// ---------------------------------------------------------------------------
// pack_w2 (v2): fragment-granular, COALESCED writes. One thread per output
// uint4 (= 8 halves of one (kb,n,q) B-fragment). Output index i == Wp4
// linear index, so stores are contiguous dwordx4 (v1 wrote isolated 2-byte
// stores at 64-B stride: ~256K write transactions, ~60 us — the hidden bulk
// of the "rest" time since R3). Loads: 8 fp32 gathers/thread; per wave and
// fixed j: 4 rows x 16 consecutive cols = 4x64B segments. L2-resident.
// Blocks 0..63 pack Wxh, 64..127 pack Whh. Block 0 zeroes the 256 flags.
// ---------------------------------------------------------------------------
__global__ __launch_bounds__(512) void pack_w2(
        const float* __restrict__ W0, __half* __restrict__ Wp0,
        const float* __restrict__ W1, __half* __restrict__ Wp1,
        unsigned int* __restrict__ flags) {
    if (blockIdx.x == 0 && threadIdx.x < 256) flags[threadIdx.x] = 0u;

    const int blk = blockIdx.x;
    const float* W  = (blk < 64) ? W0 : W1;
    uint4*      Wp4 = (uint4*)((blk < 64) ? Wp0 : Wp1);

    const int i  = (blk & 63) * 512 + threadIdx.x;  // 0..32767: uint4 index
    const int q  = i & 3;
    const int n  = (i >> 2) & 511;
    const int kb = i >> 11;
    const int k0 = kb * 32 + q * 8;

    __half h[8];
    #pragma unroll
    for (int j = 0; j < 8; ++j) h[j] = __float2half(W[(k0 + j) * 512 + n]);
    Wp4[i] = *(const uint4*)h;
}

// ---------------------------------------------------------------------------
// FUSED kernel, 544 blocks x 512 threads (VERBATIM from R9, measured
// 1367-1372 us steady-state):
//   blocks 0..31   : rnn consumer (proven R1-v2 body + 8 per-stripe gates)
//   blocks 32..543 : xw producer (proven gemm body: 128 rows x 256 cols),
//                    ordered stripe-0-first so rnn starts within ~15 us.
// ---------------------------------------------------------------------------
__global__ __launch_bounds__(512, 2) void fused_rnn(
        const float* __restrict__ X, const __half* __restrict__ WpXh,
        const float* __restrict__ bias, const uint4* __restrict__ WpHh4,
        float* __restrict__ out, unsigned int* __restrict__ flags)
{
    extern __shared__ char smem[];
    const int lane = threadIdx.x & 63;
    const int w    = threadIdx.x >> 6;   // wave 0..7
    const int q    = lane >> 4;          // quad 0..3
    const int r16  = lane & 15;

    if (blockIdx.x >= 32) {
        // ------------------- PRODUCER: xw = x @ W_xh + b -------------------
        const int g  = (int)blockIdx.x - 32;   // 0..511
        const int nb = g & 1;                  // col half
        const int sg = g >> 1;                 // 0..255 = stripe*32 + batch
        const int bg = sg & 31;                // batch
        const int st = sg >> 5;                // stripe (128 timesteps)
        const int row = bg * 1024 + st * 128 + w * 16 + r16;

        const float4* Xf4  = (const float4*)X;
        const uint4*  WpU4 = (const uint4*)WpXh;

        f32x4 acc[16];
        #pragma unroll
        for (int nt = 0; nt < 16; ++nt) acc[nt] = (f32x4){0.f, 0.f, 0.f, 0.f};

        #pragma unroll 2
        for (int kb = 0; kb < 16; ++kb) {
            float4 a0 = Xf4[row * 128 + kb * 8 + q * 2];
            float4 a1 = Xf4[row * 128 + kb * 8 + q * 2 + 1];
            f16x8 af;
            af[0] = (_Float16)a0.x; af[1] = (_Float16)a0.y;
            af[2] = (_Float16)a0.z; af[3] = (_Float16)a0.w;
            af[4] = (_Float16)a1.x; af[5] = (_Float16)a1.y;
            af[6] = (_Float16)a1.z; af[7] = (_Float16)a1.w;
            #pragma unroll
            for (int nt = 0; nt < 16; ++nt) {
                int col = nb * 256 + nt * 16 + r16;
                UU4 tmp; tmp.s = WpU4[(kb * 512 + col) * 4 + q];
                acc[nt] = __builtin_amdgcn_mfma_f32_16x16x32_f16(
                    af, __builtin_bit_cast(f16x8, tmp.v), acc[nt], 0, 0, 0);
            }
        }

        const int rbase = bg * 1024 + st * 128 + w * 16 + q * 4;
        #pragma unroll
        for (int nt = 0; nt < 16; ++nt) {
            int col = nb * 256 + nt * 16 + r16;
            float bv = bias[col];
            #pragma unroll
            for (int rr = 0; rr < 4; ++rr) {
                out[(size_t)(rbase + rr) * 512 + col] = acc[nt][rr] + bv;
            }
        }

        __syncthreads();
        if (threadIdx.x == 0) {
            __threadfence();
            __hip_atomic_fetch_add(&flags[sg], 1u, __ATOMIC_RELEASE,
                                   __HIP_MEMORY_SCOPE_AGENT);
        }
        return;
    }

    // ---------------------- CONSUMER: recurrence ----------------------
    uint4*  LBS = (uint4*)smem;                 // 8192 uint4 = 128 KB (kb 12..15)
    __half* hb  = (__half*)(smem + 131072);     // 2 x 512 halves (double buffer)

    const int b = blockIdx.x;
    const int t = threadIdx.x;    // 0..511

    // Stage streamed B-fragments (k-blocks 12..15) into LDS.
    #pragma unroll
    for (int j = 0; j < 16; ++j) {
        int kb  = 12 + (j >> 2);
        int col = w * 64 + (j & 3) * 16 + r16;
        LBS[j * 512 + t] = WpHh4[(kb * 512 + col) * 4 + q];
    }

    // Resident B-fragments: k-blocks 0..11 x 4 N-tiles = 48 uint4 / lane,
    // pinned to AGPRs (the ONLY pin budget proven correct here).
    u32x4 Bf[48];
    #pragma unroll
    for (int kb = 0; kb < 12; ++kb) {
        #pragma unroll
        for (int nt = 0; nt < 4; ++nt) {
            int col = w * 64 + nt * 16 + r16;
            UU4 tmp; tmp.s = WpHh4[(kb * 512 + col) * 4 + q];
            Bf[kb * 4 + nt] = tmp.v;
        }
    }
    #pragma unroll
    for (int i = 0; i < 48; ++i) asm volatile("" : "+a"(Bf[i]));

    float* orow = out + (size_t)b * SEQ * DIM;
    const int c = w * 64 + q * 16 + r16;   // this thread's single output col

    // Wait for stripe 0 of this batch (rows 0..127), then step 0.
    gate_wait(flags, 0 * 32 + b);

    float xw = orow[c];
    float h  = tanh_fast(xw);
    orow[c] = h;
    hb[c] = __float2half(h);
    xw = orow[DIM + c];                    // prefetch step 1's xw (stripe 0)
    __syncthreads();

    #pragma unroll 1
    for (int step = 1; step < SEQ; ++step) {
        orow += DIM;
        const __half* ha = hb + (((step & 1) ^ 1) << 9);   // h_{t-1}

        f32x4 m[4];
        #pragma unroll
        for (int i = 0; i < 4; ++i) m[i] = (f32x4){0.f, 0.f, 0.f, 0.f};

        // Streamed k-blocks first (LDS reads fill the pipe while MFMAs start).
        #pragma unroll
        for (int s = 0; s < 4; ++s) {
            f16x8 af = *(const f16x8*)(ha + (12 + s) * 32 + q * 8);
            #pragma unroll
            for (int nt = 0; nt < 4; ++nt) {
                UU4 tmp; tmp.s = LBS[(s * 4 + nt) * 512 + t];
                m[nt] = __builtin_amdgcn_mfma_f32_16x16x32_f16(
                    af, __builtin_bit_cast(f16x8, tmp.v), m[nt], 0, 0, 0);
            }
        }
        // Resident k-blocks.
        #pragma unroll
        for (int kb = 0; kb < 12; ++kb) {
            f16x8 af = *(const f16x8*)(ha + kb * 32 + q * 8);
            #pragma unroll
            for (int nt = 0; nt < 4; ++nt) {
                m[nt] = __builtin_amdgcn_mfma_f32_16x16x32_f16(
                    af, __builtin_bit_cast(f16x8, Bf[kb * 4 + nt]), m[nt], 0, 0, 0);
            }
        }

        // All acc rows equal (replicated A): tile q, reg 0 holds col c.
        float v = (q == 0 ? m[0][0] : q == 1 ? m[1][0] : q == 2 ? m[2][0] : m[3][0]) + xw;
        h = tanh_fast(v);

        orow[c] = h;
        __half* hw = hb + ((step & 1) << 9);
        hw[c] = __float2half(h);

        // Gate before the prefetch crosses into a new 128-step stripe.
        const int nstep = step + 1;
        if ((nstep & 127) == 0 && nstep < SEQ)
            gate_wait(flags, (nstep >> 7) * 32 + b);

        xw = orow[DIM + c];
        __syncthreads();
    }

    float* hf = out + (size_t)BATCH * SEQ * DIM + (size_t)b * DIM;
    hf[c] = h;
}

extern "C" void kernel_launch(void* const* d_in, const int* in_sizes, int n_in,
                              void* d_out, int out_size, void* d_ws, size_t ws_size,
                              hipStream_t stream) {
    const float* X    = (const float*)d_in[0];   // [32,1024,512] fp32
    const float* Wxh  = (const float*)d_in[1];   // [512,512] fp32
    const float* Whh  = (const float*)d_in[2];   // [512,512] fp32
    const float* bias = (const float*)d_in[3];   // [512] fp32
    float* out = (float*)d_out;

    __half* WpXh = (__half*)d_ws;                                  // 512 KB @ 0
    __half* WpHh = (__half*)((char*)d_ws + (512u << 10));          // 512 KB @ 512K
    unsigned int* flags = (unsigned int*)((char*)d_ws + (1024u << 10)); // 1 KB @ 1M

    (void)hipFuncSetAttribute((const void*)fused_rnn,
                              hipFuncAttributeMaxDynamicSharedMemorySize, 133120);

    pack_w2<<<128, 512, 0, stream>>>(Wxh, WpXh, Whh, WpHh, flags);
    fused_rnn<<<544, 512, 133120, stream>>>(X, WpXh, bias,
                                            (const uint4*)WpHh, out, flags);
}